// Round 3
// baseline (568.887 us; speedup 1.0000x reference)
//
#include <hip/hip_runtime.h>

// GraphVAE fused persistent kernel, round 3.
// R2 post-mortem: waves 1-4 loaded the X ping-pong buffer BEFORE the slot
// poll completed (only tid<20 polled; __syncthreads came after the loads)
// -> near-converged stale-read race, absmax 4.9e-4. Fix: poll -> barrier ->
// load. Also restored the two-pass BatchNorm variance (R1's exact-match
// numerics; one-pass E[x^2]-m^2 cancels).
// All cross-block traffic stays RELAXED agent-scope (sc1): no buffer_inv /
// buffer_wbl2 cache-wide ops (R1's 7us/barrier cost).

#define NN 80
#define PBLK 20            // blocks; each owns 4 columns of X
#define TPB 320            // 5 waves
#define RP 84              // LDS row pad (16B-aligned rows, bank-skewed)
#define NCOLS 13           // owned feature columns per block (ceil(256/20))

// ---- relaxed agent-scope (sc1) accessors: coherent, no cache-wide ops ----
__device__ __forceinline__ float ld_f32g(const float* p){
  return __hip_atomic_load((float*)p, __ATOMIC_RELAXED, __HIP_MEMORY_SCOPE_AGENT);
}
__device__ __forceinline__ void st_f32g(float* p, float v){
  __hip_atomic_store(p, v, __ATOMIC_RELAXED, __HIP_MEMORY_SCOPE_AGENT);
}
__device__ __forceinline__ int ld_i32g(const int* p){
  return __hip_atomic_load((int*)p, __ATOMIC_RELAXED, __HIP_MEMORY_SCOPE_AGENT);
}
__device__ __forceinline__ void st_i32g(int* p, int v){
  __hip_atomic_store(p, v, __ATOMIC_RELAXED, __HIP_MEMORY_SCOPE_AGENT);
}
__device__ __forceinline__ float2 ld_f2g(const float* p){
  union { unsigned long long u; float2 f; } c;
  c.u = __hip_atomic_load((unsigned long long*)p, __ATOMIC_RELAXED, __HIP_MEMORY_SCOPE_AGENT);
  return c.f;
}
__device__ __forceinline__ void st_f2g(float* p, float a, float b){
  union { unsigned long long u; float2 f; } c; c.f.x = a; c.f.y = b;
  __hip_atomic_store((unsigned long long*)p, c.u, __ATOMIC_RELAXED, __HIP_MEMORY_SCOPE_AGENT);
}

__device__ __forceinline__ float wave_sum(float v){
  #pragma unroll
  for (int k = 32; k >= 1; k >>= 1) v += __shfl_xor(v, k, 64);
  return v;
}

// GCN aggregate(+self loop)+bias+BatchNorm(train,biased,two-pass var)+ReLU
// for owned columns; result left in accL. inL/accL: LDS [NCOLS][80].
__device__ void gcn_bn_relu(const float* inL, const float* bias, const float* gamma,
                            const float* beta, const int* ei, const float* dinvS,
                            float* accL, float* colstat, int p, int tid)
{
  for (int u = tid; u < NCOLS*NN; u += TPB) accL[u] = 0.f;
  __syncthreads();
  for (int cl = 0; cl < NCOLS; cl++){
    int c = p + PBLK*cl; if (c >= 256) break;
    const float* col = &inL[cl*NN];
    for (int e = tid; e < 800; e += TPB){
      int s = ei[e], d = ei[800+e];
      atomicAdd(&accL[cl*NN + d], col[s]*dinvS[s]*dinvS[d]);
    }
  }
  __syncthreads();
  for (int u = tid; u < NCOLS*NN; u += TPB){
    int cl = u/NN, i = u - cl*NN, c = p + PBLK*cl;
    if (c < 256) accL[u] += inL[u]*dinvS[i]*dinvS[i] + bias[c];
  }
  __syncthreads();
  // stats: 16 lanes per column, two-pass variance (matches reference numerics)
  if (tid < 16*NCOLS){
    int g = tid >> 4, s = tid & 15, c = p + PBLK*g;
    if (c < 256){
      float r[5];
      float sm = 0.f;
      #pragma unroll
      for (int i = 0; i < 5; i++){ r[i] = accL[g*NN + s + 16*i]; sm += r[i]; }
      #pragma unroll
      for (int k = 1; k < 16; k <<= 1) sm += __shfl_xor(sm, k, 64);
      float m = sm*(1.0f/NN);
      float sq = 0.f;
      #pragma unroll
      for (int i = 0; i < 5; i++){ float d = r[i]-m; sq += d*d; }
      #pragma unroll
      for (int k = 1; k < 16; k <<= 1) sq += __shfl_xor(sq, k, 64);
      if (s == 0){
        colstat[2*g]   = m;
        colstat[2*g+1] = 1.0f/sqrtf(sq*(1.0f/NN) + 1e-5f);
      }
    }
  }
  __syncthreads();
  for (int u = tid; u < NCOLS*NN; u += TPB){
    int cl = u/NN, c = p + PBLK*cl;
    if (c < 256){
      float hv = gamma[c]*(accL[u]-colstat[2*cl])*colstat[2*cl+1] + beta[c];
      accL[u] = fmaxf(hv, 0.f);
    }
  }
  __syncthreads();
}

__global__ __launch_bounds__(TPB, 1) void gvae_fused(
    const float* __restrict__ x,  const int* __restrict__ ei, const int* __restrict__ adj,
    const float* __restrict__ eps,
    const float* __restrict__ W1, const float* __restrict__ b1, const float* __restrict__ g1, const float* __restrict__ bt1,
    const float* __restrict__ W2, const float* __restrict__ b2, const float* __restrict__ g2, const float* __restrict__ bt2,
    const float* __restrict__ Wmu,const float* __restrict__ bmu,const float* __restrict__ Wlv,const float* __restrict__ blv,
    const float* __restrict__ We1,const float* __restrict__ be1,const float* __restrict__ We2,const float* __restrict__ be2,
    float* __restrict__ out, float* __restrict__ ws)
{
  const int tid = threadIdx.x;
  const int p   = blockIdx.x;

  // ---- workspace (host memsets flags+slots to 0) ----
  int*   flag  = (int*)ws;            // [32]  phase stamps
  float* slots = ws + 32;             // [50*20] per-iter partial ||R||^2 (>0)
  float* gvS   = ws + 1056;           // [256] pooled g_vec exchange
  float* hT    = ws + 1312;           // [256*80] layer-1 output, transposed
  float* Bm    = hT + 20480;          // [80*80] B = sigmoid(A_hat), diag=1
  float* Xb0   = Bm + 6400;           // MPM ping
  float* Xb1   = Xb0 + 6400;          // MPM pong

  __shared__ float Xs[NN*RP];
  __shared__ float MtL[4*RP];
  __shared__ float red[8];
  __shared__ float scS;
  __shared__ float dinvS[NN];
  __shared__ float accL[NCOLS*NN];
  __shared__ float hL[NCOLS*NN];
  __shared__ float gv[256], zv[128], t1v[256];
  __shared__ float colstat[2*NCOLS];

  // ---------------- E0: degrees (block-redundant) ---------------------------
  for (int i = tid; i < NN; i += TPB) accL[i] = 1.0f;            // self loop
  __syncthreads();
  for (int e = tid; e < 800; e += TPB) atomicAdd(&accL[ei[800+e]], 1.0f);
  __syncthreads();
  for (int i = tid; i < NN; i += TPB) dinvS[i] = 1.0f/sqrtf(accL[i]);
  __syncthreads();

  // ---------------- E1: GEMM1 x@W1 (own cols) + GCN1 -> hT ------------------
  for (int u = tid; u < NCOLS*NN; u += TPB){
    int cl = u/NN, i = u - cl*NN, c = p + PBLK*cl;
    if (c < 256){
      float s = 0.f;
      for (int k = 0; k < 64; k++) s += x[i*64+k]*W1[k*256+c];
      hL[u] = s;
    }
  }
  __syncthreads();
  gcn_bn_relu(hL, b1, g1, bt1, ei, dinvS, accL, colstat, p, tid);
  for (int u2 = tid; u2 < 40*NCOLS; u2 += TPB){       // export own cols (sc1)
    int cl = u2/40, i2 = (u2 - cl*40)*2, c = p + PBLK*cl;
    if (c < 256) st_f2g(&hT[c*NN+i2], accL[cl*NN+i2], accL[cl*NN+i2+1]);
  }
  __syncthreads();                                     // drains export stores
  if (tid == 0) st_i32g(&flag[p], 1);

  // ---------------- E2: GEMM2 h@W2 (needs all of hT) + GCN2 + pool ----------
  if (tid < PBLK) while (ld_i32g(&flag[tid]) < 1) {}
  __syncthreads();                                     // gate ALL waves
  for (int u = tid; u < 20*NCOLS; u += TPB){
    int cl = u/20, iq = u - cl*20, c = p + PBLK*cl;
    if (c < 256){
      int i0 = 4*iq;
      float a0=0.f,a1=0.f,a2=0.f,a3=0.f;
      for (int k = 0; k < 256; k++){
        float wv = W2[k*256+c];
        float2 h01 = ld_f2g(&hT[k*NN+i0]);
        float2 h23 = ld_f2g(&hT[k*NN+i0+2]);
        a0 += h01.x*wv; a1 += h01.y*wv; a2 += h23.x*wv; a3 += h23.y*wv;
      }
      hL[cl*NN+i0+0]=a0; hL[cl*NN+i0+1]=a1; hL[cl*NN+i0+2]=a2; hL[cl*NN+i0+3]=a3;
    }
  }
  __syncthreads();
  gcn_bn_relu(hL, b2, g2, bt2, ei, dinvS, accL, colstat, p, tid);
  if (tid < 16*NCOLS){                                 // pool own cols -> gvS
    int g = tid >> 4, s = tid & 15, c = p + PBLK*g;
    if (c < 256){
      float sm = 0.f;
      #pragma unroll
      for (int i = 0; i < 5; i++) sm += accL[g*NN + s + 16*i];
      #pragma unroll
      for (int k = 1; k < 16; k <<= 1) sm += __shfl_xor(sm, k, 64);
      if (s == 0) st_f32g(&gvS[c], sm*(1.0f/NN));
    }
  }
  __syncthreads();                                     // drains gvS stores
  if (tid == 0) st_i32g(&flag[p], 2);

  // ---------------- E3: z, t1 (block-redundant; weights are inputs) ---------
  if (tid < PBLK) while (ld_i32g(&flag[tid]) < 2) {}
  __syncthreads();
  if (tid < 256) gv[tid] = ld_f32g(&gvS[tid]);
  __syncthreads();
  if (tid < 128){
    int c = tid;
    float smu = bmu[c], slv = blv[c];
    for (int k = 0; k < 256; k++){
      float g = gv[k];
      smu += g*Wmu[k*128+c];
      slv += g*Wlv[k*128+c];
    }
    slv = fminf(fmaxf(slv, -4.f), 4.f);
    zv[c] = smu + eps[c]*expf(0.5f*slv);
  }
  __syncthreads();
  if (tid < 256){
    float s = be1[tid];
    for (int k = 0; k < 128; k++) s += zv[k]*We1[k*256+tid];
    t1v[tid] = fmaxf(s, 0.f);
  }
  __syncthreads();

  // ---------------- E4: pair logits (flattened, 1 pass) -> Bm ---------------
  {
    int c0 = 79-p, c1 = 59-p, c2 = 39-p, c3 = 19-p;    // entries per owned row
    int t1b = c0+c1, t2b = t1b+c2, L = t2b+c3;
    int i = -1, j = -1;
    if      (tid < c0) { i = p;    j = p+1 +tid;        }
    else if (tid < t1b){ i = p+20; j = p+21+(tid-c0);   }
    else if (tid < t2b){ i = p+40; j = p+41+(tid-t1b);  }
    else if (tid < L)  { i = p+60; j = p+61+(tid-t2b);  }
    if (i >= 0){
      int off = i*(159-i)/2 + (j-i-1);                  // triu(k=1) flat index
      float s = be2[off];
      for (int k = 0; k < 256; k++) s += t1v[k]*We2[k*3160+off];
      float sg = 1.0f/(1.0f + expf(-s));
      st_f32g(&Bm[i*NN+j], sg);
      st_f32g(&Bm[j*NN+i], sg);
    }
    if (tid >= 316){                                    // diag = 1
      int r = tid-316, ii = p+20*r;
      st_f32g(&Bm[ii*NN+ii], 1.0f);
    }
  }
  __syncthreads();                                     // drains Bm stores
  if (tid == 0) st_i32g(&flag[p], 3);

  // ---------------- E5: per-lane register caches ----------------------------
  const int w  = tid >> 6;
  const int l  = tid & 63;
  const int il = 16*w + (l & 15);    // row i (== j in M phase)
  const int ae = l >> 4;             // local column 0..3
  const int al = 4*p + ae;           // global column a

  float4 Af[20];
  float degA = 0.f;
  #pragma unroll
  for (int c = 0; c < 20; c++){
    int j0 = 4*c;
    int4 ar = *(const int4*)&adj[il*NN+j0];
    int q0 = adj[(j0+0)*NN+il];
    int q1 = adj[(j0+1)*NN+il];
    int q2 = adj[(j0+2)*NN+il];
    int q3 = adj[(j0+3)*NN+il];
    float4 a;
    a.x = ((ar.x|q0) != 0 || il == j0+0) ? 1.f : 0.f;
    a.y = ((ar.y|q1) != 0 || il == j0+1) ? 1.f : 0.f;
    a.z = ((ar.z|q2) != 0 || il == j0+2) ? 1.f : 0.f;
    a.w = ((ar.w|q3) != 0 || il == j0+3) ? 1.f : 0.f;
    Af[c] = a;
    degA += (a.x+a.y)+(a.z+a.w);
  }

  if (tid < PBLK) while (ld_i32g(&flag[tid]) < 3) {}
  __syncthreads();                                     // gate ALL waves

  float4 Bf[20];
  float degB = 0.f;
  #pragma unroll
  for (int c = 0; c < 20; c++){
    float2 b01 = ld_f2g(&Bm[al*NN+4*c]);
    float2 b23 = ld_f2g(&Bm[al*NN+4*c+2]);
    Bf[c].x = b01.x; Bf[c].y = b01.y; Bf[c].z = b23.x; Bf[c].w = b23.y;
    degB += (b01.x+b01.y)+(b23.x+b23.y);
  }
  const float ns = 1.0f/(fabsf(degA-degB)+1.0f);
  {                                   // b==a exclusion (valid since X,B >= 0)
    if      (ae == 0) Bf[p].x = 0.f;
    else if (ae == 1) Bf[p].y = 0.f;
    else if (ae == 2) Bf[p].z = 0.f;
    else              Bf[p].w = 0.f;
  }

  // ---------------- MPM: 50 iterations, slot==flag sync ---------------------
  for (int u = tid; u < NN*RP; u += TPB) Xs[u] = 1.0f/NN;
  __syncthreads();
  float xn = 0.f;
  for (int t = 0; t < 50; t++){
    float sc = 1.0f;
    if (t > 0){
      float pv = 0.f;
      if (tid < PBLK){                // wave0 polls the 20 producer slots
        const float* sp = &slots[(t-1)*PBLK + tid];
        do { pv = ld_f32g(sp); } while (pv == 0.0f);
      }
      if (w == 0){
        float v = pv;
        #pragma unroll
        for (int k = 1; k < 32; k <<= 1) v += __shfl_xor(v, k, 64);
        if (tid == 0) scS = 1.0f/sqrtf(v);
      }
      __syncthreads();                // RACE FIX: gate ALL waves behind poll
      sc = scS;
      const float* Xsrc = ((t-1)&1) ? Xb1 : Xb0;
      #pragma unroll
      for (int q = 0; q < 10; q++){
        int p2 = tid + TPB*q;
        int j = p2/40, c2 = p2 - 40*j;
        float2 xv = ld_f2g(&Xsrc[j*NN + 2*c2]);
        Xs[j*RP + 2*c2]     = xv.x;
        Xs[j*RP + 2*c2 + 1] = xv.y;
      }
      __syncthreads();
    }

    // M[il][al] = max_{b != al} X[il][b]*B[al][b]
    float m = 0.f;
    #pragma unroll
    for (int c = 0; c < 20; c++){
      float4 xv = *(const float4*)&Xs[il*RP+4*c];
      float p0 = xv.x*Bf[c].x, p1 = xv.y*Bf[c].y, p2 = xv.z*Bf[c].z, p3 = xv.w*Bf[c].w;
      m = fmaxf(m, fmaxf(fmaxf(p0,p1), fmaxf(p2,p3)));
    }
    float xnode = Xs[il*RP+al];
    MtL[ae*RP+il] = m;
    __syncthreads();

    // edge[il][al] = sum_j A[il][j]*M[j][al] - M[il][al]   (A[i][i]=1)
    float e0=0.f,e1=0.f,e2=0.f,e3=0.f;
    #pragma unroll
    for (int c = 0; c < 20; c++){
      float4 mv = *(const float4*)&MtL[ae*RP+4*c];
      e0 += Af[c].x*mv.x; e1 += Af[c].y*mv.y; e2 += Af[c].z*mv.z; e3 += Af[c].w*mv.w;
    }
    float edge = ((e0+e1)+(e2+e3)) - m;
    xn = sc*(ns*xnode + edge);        // R_{t+1} = f(R_t/||R_t||), norm deferred

    if (t < 49){
      float* Xdst = (t&1) ? Xb1 : Xb0;
      st_f32g(&Xdst[il*NN+al], xn);
    }
    float v2 = wave_sum(xn*xn);
    if (l == 0) red[w] = v2;
    __syncthreads();                   // drains X stores of all waves
    if (tid == 0){
      float tot = ((red[0]+red[1])+(red[2]+red[3]))+red[4];
      st_f32g(&slots[t*PBLK+p], tot);  // slot is both payload and flag
    }
  }

  // final normalization of iteration 49 (xn is in registers; no global reads)
  {
    float pv = 0.f;
    if (tid < PBLK){
      const float* sp = &slots[49*PBLK + tid];
      do { pv = ld_f32g(sp); } while (pv == 0.0f);
    }
    if (w == 0){
      float v = pv;
      #pragma unroll
      for (int k = 1; k < 32; k <<= 1) v += __shfl_xor(v, k, 64);
      if (tid == 0) scS = 1.0f/sqrtf(v);
    }
    __syncthreads();
    out[il*NN+al] = xn * scS;
  }
}

extern "C" void kernel_launch(void* const* d_in, const int* in_sizes, int n_in,
                              void* d_out, int out_size, void* d_ws, size_t ws_size,
                              hipStream_t stream)
{
  (void)in_sizes; (void)n_in; (void)out_size; (void)ws_size;
  // zero flags (128B) + slots (50*20*4B) — ws is re-poisoned to 0xAA each launch
  hipMemsetAsync(d_ws, 0, 4224, stream);
  gvae_fused<<<PBLK, TPB, 0, stream>>>(
      (const float*)d_in[0],  (const int*)d_in[1],   (const int*)d_in[2],   (const float*)d_in[3],
      (const float*)d_in[4],  (const float*)d_in[5],  (const float*)d_in[6],  (const float*)d_in[7],
      (const float*)d_in[8],  (const float*)d_in[9],  (const float*)d_in[10], (const float*)d_in[11],
      (const float*)d_in[12], (const float*)d_in[13], (const float*)d_in[14], (const float*)d_in[15],
      (const float*)d_in[16], (const float*)d_in[17], (const float*)d_in[18], (const float*)d_in[19],
      (float*)d_out, (float*)d_ws);
}